// Round 3
// baseline (516.456 us; speedup 1.0000x reference)
//
#include <hip/hip_runtime.h>

#define B_   4
#define S_   1024
#define D_   1024
#define H_   16
#define HD_  64

typedef __bf16 bf16_t;
typedef __attribute__((ext_vector_type(8))) __bf16 bf16x8;
typedef __attribute__((ext_vector_type(4))) float f32x4;

#define MFMA16(a, b, c) __builtin_amdgcn_mfma_f32_16x16x32_bf16((a), (b), (c), 0, 0, 0)

__device__ inline unsigned short f2bf(float f) {
    unsigned int u = __builtin_bit_cast(unsigned int, f);
    u += 0x7FFFu + ((u >> 16) & 1u);   // RNE
    return (unsigned short)(u >> 16);
}

__device__ inline bf16x8 ld_frag(const unsigned short* p) {
    uint4 u = *(const uint4*)p;
    return __builtin_bit_cast(bf16x8, u);
}

// async global->LDS, 16B per lane. LDS dest is wave-uniform base + lane*16.
__device__ inline void gload_lds16(const unsigned short* g, unsigned short* l) {
    __builtin_amdgcn_global_load_lds(
        (const __attribute__((address_space(1))) void*)g,
        (__attribute__((address_space(3))) void*)l,
        16, 0, 0);
}

// ---------------------------------------------------------------------------
// Elementwise fp32 -> bf16 (x). One float4 per thread.
// ---------------------------------------------------------------------------
__global__ __launch_bounds__(256) void convert_f32_bf16(
    const float* __restrict__ in, unsigned short* __restrict__ out)
{
    const size_t idx = (size_t)blockIdx.x * 256 + threadIdx.x;
    float4 v = *(const float4*)(in + idx * 4);
    unsigned short* o = out + idx * 4;
    ushort4 r;
    r.x = f2bf(v.x); r.y = f2bf(v.y); r.z = f2bf(v.z); r.w = f2bf(v.w);
    *(ushort4*)o = r;
}

// ---------------------------------------------------------------------------
// Transpose + convert: in fp32 [K][N] -> out bf16 [N][K]. 64x64 tiles.
// ---------------------------------------------------------------------------
__global__ __launch_bounds__(256) void transpose_f32_bf16(
    const float* __restrict__ in, unsigned short* __restrict__ out,
    int K, int N)
{
    __shared__ float T[64][65];
    const int tid = threadIdx.x;
    const int k0 = blockIdx.y * 64, n0 = blockIdx.x * 64;
#pragma unroll
    for (int i = 0; i < 4; ++i) {
        int c = tid + i * 256;
        int row = c >> 4, col = (c & 15) << 2;
        float4 v = *(const float4*)(in + (size_t)(k0 + row) * N + n0 + col);
        T[row][col + 0] = v.x; T[row][col + 1] = v.y;
        T[row][col + 2] = v.z; T[row][col + 3] = v.w;
    }
    __syncthreads();
#pragma unroll
    for (int i = 0; i < 4; ++i) {
        int c = tid + i * 256;
        int nr = c >> 4, kc = (c & 15) << 2;
        ushort4 r;
        r.x = f2bf(T[kc + 0][nr]); r.y = f2bf(T[kc + 1][nr]);
        r.z = f2bf(T[kc + 2][nr]); r.w = f2bf(T[kc + 3][nr]);
        *(ushort4*)(out + (size_t)(n0 + nr) * K + k0 + kc) = r;
    }
}

// ---------------------------------------------------------------------------
// bf16 MFMA GEMM: C[M,N] = A[M,K] @ Bt[N,K]^T + bias.
// 128x128 tile, 4 waves (2x2). Staging: global_load_lds width-16, linear
// LDS [128][64] (m97 structure; bank aliasing eaten — T2 null at 2-phase).
// MODE 0 (QKV): q (pre-scaled 1/8), k -> qk[row][head*128 + 0..127] (bf16),
//               v -> vt[(b*16+head)][dim][key] (bf16, transposed scatter).
// MODE 1: fp32 out[M][N].
// ---------------------------------------------------------------------------
template<int MODE>
__global__ __launch_bounds__(256) void gemm_bf16(
    const unsigned short* __restrict__ A,
    const unsigned short* __restrict__ Bt,
    const float* __restrict__ bias,
    unsigned short* __restrict__ qk,
    unsigned short* __restrict__ vt,
    float* __restrict__ out,
    int K, int N)
{
    __shared__ unsigned short Alds[128][64];
    __shared__ unsigned short Blds[128][64];
    const int tid  = threadIdx.x;
    const int l    = tid & 63, w = tid >> 6;
    const int wm   = w >> 1, wn = w & 1;
    const int quad = l >> 4, n16 = l & 15;
    const int bm = blockIdx.y * 128, bn = blockIdx.x * 128;

    const int lrow = l >> 3;            // 0..7 within an 8-row chunk
    const int lcol = (l & 7) << 3;      // ushort col 0..56

    const f32x4 zero4 = {0.f, 0.f, 0.f, 0.f};
    f32x4 acc[4][4];
#pragma unroll
    for (int i = 0; i < 4; ++i)
#pragma unroll
        for (int j = 0; j < 4; ++j) acc[i][j] = zero4;

    for (int k0 = 0; k0 < K; k0 += 64) {
        // async stage: each wave covers 4 x 1KB chunks of A and of B
#pragma unroll
        for (int i = 0; i < 4; ++i) {
            const int c8  = (w * 4 + i) * 8;        // chunk base row
            const int row = c8 + lrow;
            gload_lds16(A  + (size_t)(bm + row) * K + k0 + lcol, &Alds[c8][0]);
            gload_lds16(Bt + (size_t)(bn + row) * K + k0 + lcol, &Blds[c8][0]);
        }
        __syncthreads();
#pragma unroll
        for (int kk = 0; kk < 2; ++kk) {
            const int kc = kk * 32 + quad * 8;
            bf16x8 af[4], bfv[4];
#pragma unroll
            for (int i = 0; i < 4; ++i) af[i]  = ld_frag(&Alds[wm * 64 + i * 16 + n16][kc]);
#pragma unroll
            for (int j = 0; j < 4; ++j) bfv[j] = ld_frag(&Blds[wn * 64 + j * 16 + n16][kc]);
#pragma unroll
            for (int i = 0; i < 4; ++i)
#pragma unroll
                for (int j = 0; j < 4; ++j)
                    acc[i][j] = MFMA16(af[i], bfv[j], acc[i][j]);
        }
        __syncthreads();
    }

    // epilogue
#pragma unroll
    for (int j = 0; j < 4; ++j) {
        const int col0 = bn + wn * 64 + j * 16;
        const int col  = col0 + n16;
        const float bv = bias ? bias[col] : 0.f;
        if (MODE == 0) {
            const int head = col0 / 192;
            const int rem  = col0 % 192;
            if (rem < 128) {
                // q columns (rem<64) carry the 1/sqrt(hd) logit scale so
                // attn_fused skips the per-logit multiply (exact in bf16).
                const float sc = (rem < 64) ? 0.125f : 1.0f;
#pragma unroll
                for (int i = 0; i < 4; ++i)
#pragma unroll
                    for (int r = 0; r < 4; ++r) {
                        int row = bm + wm * 64 + i * 16 + quad * 4 + r;
                        qk[(size_t)row * 2048 + head * 128 + rem + n16] =
                            f2bf((acc[i][j][r] + bv) * sc);
                    }
            } else {
                const int dim = rem - 128 + n16;
#pragma unroll
                for (int i = 0; i < 4; ++i)
#pragma unroll
                    for (int r = 0; r < 4; ++r) {
                        int row = bm + wm * 64 + i * 16 + quad * 4 + r;
                        vt[(size_t)(((row >> 10) << 4) + head) * 65536 +
                           (size_t)dim * 1024 + (row & 1023)] =
                            f2bf(acc[i][j][r] + bv);
                    }
            }
        } else {
#pragma unroll
            for (int i = 0; i < 4; ++i)
#pragma unroll
                for (int r = 0; r < 4; ++r) {
                    int row = bm + wm * 64 + i * 16 + quad * 4 + r;
                    out[(size_t)row * N + col] = acc[i][j][r] + bv;
                }
        }
    }
}

// ---------------------------------------------------------------------------
// Fused attention: per block = 16 Q-rows of one (b,h).  (Session-best
// structure: LDS-staged K/V, single-buffered — reverted from r1/r2 variants.)
// Phase 1: QK^T via MFMA, Phase 2: register softmax, Phase 3: AV via MFMA.
// Grid (S/16, B*H), 256 threads = 4 waves.
// ---------------------------------------------------------------------------
__global__ __launch_bounds__(256) void attn_fused(
    const unsigned short* __restrict__ qk,   // [4096][2048]
    const unsigned short* __restrict__ vt,   // [64][64][1024]
    float* __restrict__ attn,                // [64][1024][1024]
    unsigned short* __restrict__ values)     // [4096][1024]
{
    __shared__ unsigned short Klds[64][72];
    __shared__ unsigned short Vlds[64][72];
    __shared__ unsigned short Plds[16][1032];
    __shared__ float redbuf[2][4][16];

    const int qb = blockIdx.x, bh = blockIdx.y;
    const int b = bh >> 4, h = bh & 15;
    const int tid = threadIdx.x, l = tid & 63, w = tid >> 6;
    const int quad = l >> 4, n16 = l & 15;

    // preload Q A-frags (q already scaled by 1/8 in gemm<0> epilogue)
    bf16x8 qf[2];
    {
        const unsigned short* qbase =
            qk + (size_t)(b * 1024 + qb * 16 + n16) * 2048 + h * 128 + quad * 8;
        qf[0] = ld_frag(qbase);
        qf[1] = ld_frag(qbase + 32);
    }

    const f32x4 zero4 = {0.f, 0.f, 0.f, 0.f};
    f32x4 c[16];
#pragma unroll
    for (int s = 0; s < 16; ++s) c[s] = zero4;

    // ---- Phase 1: QK^T ----
    const unsigned short* kbase = qk + (size_t)(b * 1024) * 2048 + h * 128 + 64;
    for (int s = 0; s < 16; ++s) {
#pragma unroll
        for (int i = 0; i < 2; ++i) {
            int cc = tid + i * 256;
            int key = cc >> 3, off = (cc & 7) << 3;
            *(uint4*)&Klds[key][off] =
                *(const uint4*)(kbase + (size_t)(s * 64 + key) * 2048 + off);
        }
        __syncthreads();
        const int krow = w * 16 + n16;
        bf16x8 k0f = ld_frag(&Klds[krow][quad * 8]);
        bf16x8 k1f = ld_frag(&Klds[krow][32 + quad * 8]);
        c[s] = MFMA16(qf[0], k0f, c[s]);
        c[s] = MFMA16(qf[1], k1f, c[s]);
        __syncthreads();
    }

    // ---- Phase 2: softmax in registers ----
    float mx[4] = {-1e30f, -1e30f, -1e30f, -1e30f};
#pragma unroll
    for (int s = 0; s < 16; ++s)
#pragma unroll
        for (int r = 0; r < 4; ++r)
            mx[r] = fmaxf(mx[r], c[s][r]);
#pragma unroll
    for (int off = 1; off <= 8; off <<= 1)
#pragma unroll
        for (int r = 0; r < 4; ++r)
            mx[r] = fmaxf(mx[r], __shfl_xor(mx[r], off, 64));
    if (n16 == 0)
#pragma unroll
        for (int r = 0; r < 4; ++r) redbuf[0][w][quad * 4 + r] = mx[r];
    __syncthreads();
#pragma unroll
    for (int r = 0; r < 4; ++r) {
        const int row = quad * 4 + r;
        float m = redbuf[0][0][row];
        m = fmaxf(m, redbuf[0][1][row]);
        m = fmaxf(m, redbuf[0][2][row]);
        m = fmaxf(m, redbuf[0][3][row]);
        mx[r] = m;
    }

    float sm[4] = {0.f, 0.f, 0.f, 0.f};
#pragma unroll
    for (int s = 0; s < 16; ++s)
#pragma unroll
        for (int r = 0; r < 4; ++r) {
            float e = __expf(c[s][r] - mx[r]);
            c[s][r] = e;
            sm[r] += e;
        }
#pragma unroll
    for (int off = 1; off <= 8; off <<= 1)
#pragma unroll
        for (int r = 0; r < 4; ++r)
            sm[r] += __shfl_xor(sm[r], off, 64);
    if (n16 == 0)
#pragma unroll
        for (int r = 0; r < 4; ++r) redbuf[1][w][quad * 4 + r] = sm[r];
    __syncthreads();
    float inv[4];
#pragma unroll
    for (int r = 0; r < 4; ++r) {
        const int row = quad * 4 + r;
        inv[r] = 1.f / (redbuf[1][0][row] + redbuf[1][1][row] +
                        redbuf[1][2][row] + redbuf[1][3][row]);
    }

    // write attention (fp32) + P (bf16 to LDS for AV)
    float* abase = attn + ((size_t)bh * 1024 + qb * 16) * 1024;
#pragma unroll
    for (int s = 0; s < 16; ++s)
#pragma unroll
        for (int r = 0; r < 4; ++r) {
            const float a = c[s][r] * inv[r];
            const int row = quad * 4 + r;
            const int key = s * 64 + w * 16 + n16;
            abase[(size_t)row * 1024 + key] = a;
            Plds[row][key] = f2bf(a);
        }

    // ---- Phase 3: AV ----
    f32x4 o = zero4;
    const unsigned short* vbase = vt + (size_t)bh * 65536;
    for (int s = 0; s < 16; ++s) {
#pragma unroll
        for (int i = 0; i < 2; ++i) {
            int cc = tid + i * 256;
            int dim = cc >> 3, off = (cc & 7) << 3;
            *(uint4*)&Vlds[dim][off] =
                *(const uint4*)(vbase + (size_t)dim * 1024 + s * 64 + off);
        }
        __syncthreads();
#pragma unroll
        for (int kk = 0; kk < 2; ++kk) {
            bf16x8 pf = ld_frag(&Plds[n16][s * 64 + kk * 32 + quad * 8]);
            bf16x8 vf = ld_frag(&Vlds[w * 16 + n16][kk * 32 + quad * 8]);
            o = MFMA16(pf, vf, o);
        }
        __syncthreads();
    }

#pragma unroll
    for (int r = 0; r < 4; ++r) {
        const int row = quad * 4 + r;
        values[(size_t)(b * 1024 + qb * 16 + row) * 1024 + h * 64 + w * 16 + n16] =
            f2bf(o[r]);
    }
}

// ---------------------------------------------------------------------------
extern "C" void kernel_launch(void* const* d_in, const int* in_sizes, int n_in,
                              void* d_out, int out_size, void* d_ws, size_t ws_size,
                              hipStream_t stream)
{
    const float* x     = (const float*)d_in[0];   // [4,1024,1024]
    const float* W_qkv = (const float*)d_in[1];   // [1024,3072]
    const float* b_qkv = (const float*)d_in[2];   // [3072]
    const float* W_o   = (const float*)d_in[3];   // [1024,1024]
    const float* b_o   = (const float*)d_in[4];   // [1024]

    float* o_out    = (float*)d_out;                          // [4096,1024] fp32
    float* attn_out = o_out + (size_t)B_ * S_ * D_;           // [64,1024,1024] fp32

    const size_t M1 = 1ull << 20;
    unsigned short* ws      = (unsigned short*)d_ws;
    unsigned short* x_bf    = ws;                 // 4M  [4096][1024]
    unsigned short* wqkvt   = ws + 4 * M1;        // 3M  [3072][1024]
    unsigned short* wot     = ws + 7 * M1;        // 1M  [1024][1024]
    unsigned short* qkbuf   = ws + 8 * M1;        // 8M  [4096][2048]
    unsigned short* vtbuf   = ws + 16 * M1;       // 4M  [64][64][1024]
    unsigned short* valbuf  = ws + 20 * M1;       // 4M  [4096][1024]

    convert_f32_bf16<<<4096, 256, 0, stream>>>(x, x_bf);
    transpose_f32_bf16<<<dim3(3072 / 64, 1024 / 64), 256, 0, stream>>>(W_qkv, wqkvt, 1024, 3072);
    transpose_f32_bf16<<<dim3(1024 / 64, 1024 / 64), 256, 0, stream>>>(W_o, wot, 1024, 1024);

    gemm_bf16<0><<<dim3(3072 / 128, 4096 / 128), 256, 0, stream>>>(
        x_bf, wqkvt, b_qkv, qkbuf, vtbuf, nullptr, 1024, 3072);

    attn_fused<<<dim3(S_ / 16, B_ * H_), 256, 0, stream>>>(
        qkbuf, vtbuf, attn_out, valbuf);

    gemm_bf16<1><<<dim3(1024 / 128, 4096 / 128), 256, 0, stream>>>(
        valbuf, wot, b_o, nullptr, nullptr, o_out, 1024, 1024);
}

// Round 4
// 472.129 us; speedup vs baseline: 1.0939x; 1.0939x over previous
//
#include <hip/hip_runtime.h>

#define B_   4
#define S_   1024
#define D_   1024
#define H_   16
#define HD_  64

typedef __bf16 bf16_t;
typedef __attribute__((ext_vector_type(8))) __bf16 bf16x8;
typedef __attribute__((ext_vector_type(4))) float f32x4;

#define MFMA16(a, b, c) __builtin_amdgcn_mfma_f32_16x16x32_bf16((a), (b), (c), 0, 0, 0)

__device__ inline unsigned short f2bf(float f) {
    unsigned int u = __builtin_bit_cast(unsigned int, f);
    u += 0x7FFFu + ((u >> 16) & 1u);   // RNE
    return (unsigned short)(u >> 16);
}

__device__ inline bf16x8 ld_frag(const unsigned short* p) {
    uint4 u = *(const uint4*)p;
    return __builtin_bit_cast(bf16x8, u);
}

// ---------------------------------------------------------------------------
// Elementwise fp32 -> bf16 (x). One float4 per thread.
// ---------------------------------------------------------------------------
__global__ __launch_bounds__(256) void convert_f32_bf16(
    const float* __restrict__ in, unsigned short* __restrict__ out)
{
    const size_t idx = (size_t)blockIdx.x * 256 + threadIdx.x;
    float4 v = *(const float4*)(in + idx * 4);
    unsigned short* o = out + idx * 4;
    ushort4 r;
    r.x = f2bf(v.x); r.y = f2bf(v.y); r.z = f2bf(v.z); r.w = f2bf(v.w);
    *(ushort4*)o = r;
}

// ---------------------------------------------------------------------------
// Transpose + convert: in fp32 [K][N] -> out bf16 [N][K]. 64x64 tiles.
// ---------------------------------------------------------------------------
__global__ __launch_bounds__(256) void transpose_f32_bf16(
    const float* __restrict__ in, unsigned short* __restrict__ out,
    int K, int N)
{
    __shared__ float T[64][65];
    const int tid = threadIdx.x;
    const int k0 = blockIdx.y * 64, n0 = blockIdx.x * 64;
#pragma unroll
    for (int i = 0; i < 4; ++i) {
        int c = tid + i * 256;
        int row = c >> 4, col = (c & 15) << 2;
        float4 v = *(const float4*)(in + (size_t)(k0 + row) * N + n0 + col);
        T[row][col + 0] = v.x; T[row][col + 1] = v.y;
        T[row][col + 2] = v.z; T[row][col + 3] = v.w;
    }
    __syncthreads();
#pragma unroll
    for (int i = 0; i < 4; ++i) {
        int c = tid + i * 256;
        int nr = c >> 4, kc = (c & 15) << 2;
        ushort4 r;
        r.x = f2bf(T[kc + 0][nr]); r.y = f2bf(T[kc + 1][nr]);
        r.z = f2bf(T[kc + 2][nr]); r.w = f2bf(T[kc + 3][nr]);
        *(ushort4*)(out + (size_t)(n0 + nr) * K + k0 + kc) = r;
    }
}

// ---------------------------------------------------------------------------
// bf16 transpose of V into per-(b,h) key-major layout:
// v [4096][1024] (col = h*64+dim)  ->  vt [bh][dim][key].
// Grid (S/64, B*H), 256 threads.
// ---------------------------------------------------------------------------
__global__ __launch_bounds__(256) void transpose_v_bf16(
    const unsigned short* __restrict__ v,
    unsigned short* __restrict__ vt)
{
    __shared__ unsigned short T[64][65];
    const int tid = threadIdx.x;
    const int kt = blockIdx.x, bh = blockIdx.y;
    const int b = bh >> 4, h = bh & 15;
#pragma unroll
    for (int i = 0; i < 2; ++i) {
        const int c = tid + i * 256;
        const int key = c >> 3, off = (c & 7) << 3;
        uint4 u = *(const uint4*)(v + (size_t)(b * 1024 + kt * 64 + key) * 1024 + h * 64 + off);
        union { uint4 u4; unsigned short us[8]; } uu; uu.u4 = u;
#pragma unroll
        for (int t = 0; t < 8; ++t) T[key][off + t] = uu.us[t];
    }
    __syncthreads();
#pragma unroll
    for (int i = 0; i < 16; ++i) {
        const int c = tid + i * 256;          // 0..4095
        const int dim = c >> 6, key = c & 63;
        vt[((size_t)bh * 64 + dim) * 1024 + kt * 64 + key] = T[key][dim];
    }
}

// ---------------------------------------------------------------------------
// bf16 MFMA GEMM: C[M,N] = A[M,K] @ Bt[N,K]^T + bias.
// 128x128 tile, 4 waves (2x2). Staging: REG-STAGED uint4 copies into padded
// LDS [128][72] (conflict-free ds_read; the R0 proven-fastest structure —
// gload_lds+linear LDS measured +39us worse here, R3).
// MODE 0 (QKV): q (pre-scaled 1/8), k -> qk[row][head*128 + 0..127];
//               v -> vnat[row][head*64+dim] (coalesced; transposed later).
// MODE 1: fp32 out[M][N].
// ---------------------------------------------------------------------------
template<int MODE>
__global__ __launch_bounds__(256) void gemm_bf16(
    const unsigned short* __restrict__ A,
    const unsigned short* __restrict__ Bt,
    const float* __restrict__ bias,
    unsigned short* __restrict__ qk,
    unsigned short* __restrict__ vnat,
    float* __restrict__ out,
    int K, int N)
{
    __shared__ unsigned short Alds[128][72];
    __shared__ unsigned short Blds[128][72];
    const int tid  = threadIdx.x;
    const int l    = tid & 63, w = tid >> 6;
    const int wm   = w >> 1, wn = w & 1;
    const int quad = l >> 4, n16 = l & 15;
    const int bm = blockIdx.y * 128, bn = blockIdx.x * 128;

    const f32x4 zero4 = {0.f, 0.f, 0.f, 0.f};
    f32x4 acc[4][4];
#pragma unroll
    for (int i = 0; i < 4; ++i)
#pragma unroll
        for (int j = 0; j < 4; ++j) acc[i][j] = zero4;

    for (int k0 = 0; k0 < K; k0 += 64) {
#pragma unroll
        for (int i = 0; i < 4; ++i) {
            int c = tid + i * 256;
            int row = c >> 3, off = (c & 7) << 3;
            *(uint4*)&Alds[row][off] = *(const uint4*)(A + (size_t)(bm + row) * K + k0 + off);
            *(uint4*)&Blds[row][off] = *(const uint4*)(Bt + (size_t)(bn + row) * K + k0 + off);
        }
        __syncthreads();
#pragma unroll
        for (int kk = 0; kk < 2; ++kk) {
            const int kc = kk * 32 + quad * 8;
            bf16x8 af[4], bfv[4];
#pragma unroll
            for (int i = 0; i < 4; ++i) af[i]  = ld_frag(&Alds[wm * 64 + i * 16 + n16][kc]);
#pragma unroll
            for (int j = 0; j < 4; ++j) bfv[j] = ld_frag(&Blds[wn * 64 + j * 16 + n16][kc]);
#pragma unroll
            for (int i = 0; i < 4; ++i)
#pragma unroll
                for (int j = 0; j < 4; ++j)
                    acc[i][j] = MFMA16(af[i], bfv[j], acc[i][j]);
        }
        __syncthreads();
    }

    // epilogue
#pragma unroll
    for (int j = 0; j < 4; ++j) {
        const int col0 = bn + wn * 64 + j * 16;
        const int col  = col0 + n16;
        const float bv = bias ? bias[col] : 0.f;
        if (MODE == 0) {
            const int head = col0 / 192;
            const int rem  = col0 % 192;
            if (rem < 128) {
                // q columns (rem<64) carry the 1/sqrt(hd) logit scale so
                // attn_fused skips the per-logit multiply (exact in bf16).
                const float sc = (rem < 64) ? 0.125f : 1.0f;
#pragma unroll
                for (int i = 0; i < 4; ++i)
#pragma unroll
                    for (int r = 0; r < 4; ++r) {
                        int row = bm + wm * 64 + i * 16 + quad * 4 + r;
                        qk[(size_t)row * 2048 + head * 128 + rem + n16] =
                            f2bf((acc[i][j][r] + bv) * sc);
                    }
            } else {
                const int dcol = head * 64 + (rem - 128) + n16;
#pragma unroll
                for (int i = 0; i < 4; ++i)
#pragma unroll
                    for (int r = 0; r < 4; ++r) {
                        int row = bm + wm * 64 + i * 16 + quad * 4 + r;
                        vnat[(size_t)row * 1024 + dcol] = f2bf(acc[i][j][r] + bv);
                    }
            }
        } else {
#pragma unroll
            for (int i = 0; i < 4; ++i)
#pragma unroll
                for (int r = 0; r < 4; ++r) {
                    int row = bm + wm * 64 + i * 16 + quad * 4 + r;
                    out[(size_t)row * N + col] = acc[i][j][r] + bv;
                }
        }
    }
}

// ---------------------------------------------------------------------------
// Fused attention: per block = 16 Q-rows of one (b,h).
// Phase 1: QK^T via MFMA, double-buffered K staging (1 barrier/round).
// Phase 2: register softmax (q pre-scaled; no logit multiply).
// Phase 3: AV via MFMA, double-buffered V staging.
// K/V staging buffers unioned (phases disjoint). Grid (S/16, B*H), 4 waves.
// ---------------------------------------------------------------------------
__global__ __launch_bounds__(256) void attn_fused(
    const unsigned short* __restrict__ qk,   // [4096][2048]
    const unsigned short* __restrict__ vt,   // [64][64][1024]
    float* __restrict__ attn,                // [64][1024][1024]
    unsigned short* __restrict__ values)     // [4096][1024]
{
    __shared__ unsigned short KV[2][64][72];
    __shared__ unsigned short Plds[16][1032];
    __shared__ float redbuf[2][4][16];

    const int qb = blockIdx.x, bh = blockIdx.y;
    const int b = bh >> 4, h = bh & 15;
    const int tid = threadIdx.x, l = tid & 63, w = tid >> 6;
    const int quad = l >> 4, n16 = l & 15;

    const int skey = tid >> 3;          // 0..31
    const int soff = (tid & 7) << 3;    // 0..56

    // preload Q A-frags (q already scaled by 1/8 in gemm<0> epilogue)
    bf16x8 qf[2];
    {
        const unsigned short* qbase =
            qk + (size_t)(b * 1024 + qb * 16 + n16) * 2048 + h * 128 + quad * 8;
        qf[0] = ld_frag(qbase);
        qf[1] = ld_frag(qbase + 32);
    }

    const f32x4 zero4 = {0.f, 0.f, 0.f, 0.f};
    f32x4 c[16];
#pragma unroll
    for (int s = 0; s < 16; ++s) c[s] = zero4;

    // ---- Phase 1: QK^T, double-buffered ----
    const unsigned short* kbase = qk + (size_t)(b * 1024) * 2048 + h * 128 + 64;
#pragma unroll
    for (int i = 0; i < 2; ++i)
        *(uint4*)&KV[0][skey + i * 32][soff] =
            *(const uint4*)(kbase + (size_t)(skey + i * 32) * 2048 + soff);
    __syncthreads();
    for (int s = 0; s < 16; ++s) {
        if (s < 15) {
#pragma unroll
            for (int i = 0; i < 2; ++i)
                *(uint4*)&KV[(s + 1) & 1][skey + i * 32][soff] =
                    *(const uint4*)(kbase +
                        (size_t)((s + 1) * 64 + skey + i * 32) * 2048 + soff);
        }
        const int p = s & 1;
        const int krow = w * 16 + n16;
        bf16x8 k0f = ld_frag(&KV[p][krow][quad * 8]);
        bf16x8 k1f = ld_frag(&KV[p][krow][32 + quad * 8]);
        c[s] = MFMA16(qf[0], k0f, c[s]);
        c[s] = MFMA16(qf[1], k1f, c[s]);
        __syncthreads();
    }

    // ---- Phase 2: softmax in registers ----
    float mx[4] = {-1e30f, -1e30f, -1e30f, -1e30f};
#pragma unroll
    for (int s = 0; s < 16; ++s)
#pragma unroll
        for (int r = 0; r < 4; ++r)
            mx[r] = fmaxf(mx[r], c[s][r]);
#pragma unroll
    for (int off = 1; off <= 8; off <<= 1)
#pragma unroll
        for (int r = 0; r < 4; ++r)
            mx[r] = fmaxf(mx[r], __shfl_xor(mx[r], off, 64));
    if (n16 == 0)
#pragma unroll
        for (int r = 0; r < 4; ++r) redbuf[0][w][quad * 4 + r] = mx[r];
    __syncthreads();
#pragma unroll
    for (int r = 0; r < 4; ++r) {
        const int row = quad * 4 + r;
        float m = redbuf[0][0][row];
        m = fmaxf(m, redbuf[0][1][row]);
        m = fmaxf(m, redbuf[0][2][row]);
        m = fmaxf(m, redbuf[0][3][row]);
        mx[r] = m;
    }

    float sm[4] = {0.f, 0.f, 0.f, 0.f};
#pragma unroll
    for (int s = 0; s < 16; ++s)
#pragma unroll
        for (int r = 0; r < 4; ++r) {
            float e = __expf(c[s][r] - mx[r]);
            c[s][r] = e;
            sm[r] += e;
        }
#pragma unroll
    for (int off = 1; off <= 8; off <<= 1)
#pragma unroll
        for (int r = 0; r < 4; ++r)
            sm[r] += __shfl_xor(sm[r], off, 64);
    if (n16 == 0)
#pragma unroll
        for (int r = 0; r < 4; ++r) redbuf[1][w][quad * 4 + r] = sm[r];
    __syncthreads();
    float inv[4];
#pragma unroll
    for (int r = 0; r < 4; ++r) {
        const int row = quad * 4 + r;
        inv[r] = 1.f / (redbuf[1][0][row] + redbuf[1][1][row] +
                        redbuf[1][2][row] + redbuf[1][3][row]);
    }

    // write attention (fp32) + P (bf16 to LDS for AV)
    float* abase = attn + ((size_t)bh * 1024 + qb * 16) * 1024;
#pragma unroll
    for (int s = 0; s < 16; ++s)
#pragma unroll
        for (int r = 0; r < 4; ++r) {
            const float a = c[s][r] * inv[r];
            const int row = quad * 4 + r;
            const int key = s * 64 + w * 16 + n16;
            abase[(size_t)row * 1024 + key] = a;
            Plds[row][key] = f2bf(a);
        }

    // ---- Phase 3: AV, double-buffered ----
    f32x4 o = zero4;
    const unsigned short* vbase = vt + (size_t)bh * 65536;
#pragma unroll
    for (int i = 0; i < 2; ++i)
        *(uint4*)&KV[0][skey + i * 32][soff] =
            *(const uint4*)(vbase + (size_t)(skey + i * 32) * 1024 + soff);
    __syncthreads();
    for (int s = 0; s < 16; ++s) {
        if (s < 15) {
#pragma unroll
            for (int i = 0; i < 2; ++i)
                *(uint4*)&KV[(s + 1) & 1][skey + i * 32][soff] =
                    *(const uint4*)(vbase +
                        (size_t)(skey + i * 32) * 1024 + (s + 1) * 64 + soff);
        }
        const int p = s & 1;
#pragma unroll
        for (int kk = 0; kk < 2; ++kk) {
            bf16x8 pf = ld_frag(&Plds[n16][s * 64 + kk * 32 + quad * 8]);
            bf16x8 vf = ld_frag(&KV[p][w * 16 + n16][kk * 32 + quad * 8]);
            o = MFMA16(pf, vf, o);
        }
        __syncthreads();
    }

#pragma unroll
    for (int r = 0; r < 4; ++r) {
        const int row = quad * 4 + r;
        values[(size_t)(b * 1024 + qb * 16 + row) * 1024 + h * 64 + w * 16 + n16] =
            f2bf(o[r]);
    }
}

// ---------------------------------------------------------------------------
extern "C" void kernel_launch(void* const* d_in, const int* in_sizes, int n_in,
                              void* d_out, int out_size, void* d_ws, size_t ws_size,
                              hipStream_t stream)
{
    const float* x     = (const float*)d_in[0];   // [4,1024,1024]
    const float* W_qkv = (const float*)d_in[1];   // [1024,3072]
    const float* b_qkv = (const float*)d_in[2];   // [3072]
    const float* W_o   = (const float*)d_in[3];   // [1024,1024]
    const float* b_o   = (const float*)d_in[4];   // [1024]

    float* o_out    = (float*)d_out;                          // [4096,1024] fp32
    float* attn_out = o_out + (size_t)B_ * S_ * D_;           // [64,1024,1024] fp32

    const size_t M1 = 1ull << 20;
    unsigned short* ws      = (unsigned short*)d_ws;
    unsigned short* x_bf    = ws;                 // 4M  [4096][1024]
    unsigned short* wqkvt   = ws + 4 * M1;        // 3M  [3072][1024]
    unsigned short* wot     = ws + 7 * M1;        // 1M  [1024][1024]
    unsigned short* qkbuf   = ws + 8 * M1;        // 8M  [4096][2048]
    unsigned short* vtbuf   = ws + 16 * M1;       // 4M  [64][64][1024]
    unsigned short* valbuf  = ws + 20 * M1;       // 4M  [4096][1024] (vnat, then values)

    convert_f32_bf16<<<4096, 256, 0, stream>>>(x, x_bf);
    transpose_f32_bf16<<<dim3(3072 / 64, 1024 / 64), 256, 0, stream>>>(W_qkv, wqkvt, 1024, 3072);
    transpose_f32_bf16<<<dim3(1024 / 64, 1024 / 64), 256, 0, stream>>>(W_o, wot, 1024, 1024);

    gemm_bf16<0><<<dim3(3072 / 128, 4096 / 128), 256, 0, stream>>>(
        x_bf, wqkvt, b_qkv, qkbuf, valbuf, nullptr, 1024, 3072);

    transpose_v_bf16<<<dim3(S_ / 64, B_ * H_), 256, 0, stream>>>(valbuf, vtbuf);

    attn_fused<<<dim3(S_ / 16, B_ * H_), 256, 0, stream>>>(
        qkbuf, vtbuf, attn_out, valbuf);

    gemm_bf16<1><<<dim3(1024 / 128, 4096 / 128), 256, 0, stream>>>(
        valbuf, wot, b_o, nullptr, nullptr, o_out, 1024, 1024);
}

// Round 5
// 442.161 us; speedup vs baseline: 1.1680x; 1.0678x over previous
//
#include <hip/hip_runtime.h>

#define B_   4
#define S_   1024
#define D_   1024
#define H_   16
#define HD_  64

typedef __bf16 bf16_t;
typedef __attribute__((ext_vector_type(8))) __bf16 bf16x8;
typedef __attribute__((ext_vector_type(4))) float f32x4;

#define MFMA16(a, b, c) __builtin_amdgcn_mfma_f32_16x16x32_bf16((a), (b), (c), 0, 0, 0)

__device__ inline unsigned short f2bf(float f) {
    unsigned int u = __builtin_bit_cast(unsigned int, f);
    u += 0x7FFFu + ((u >> 16) & 1u);   // RNE
    return (unsigned short)(u >> 16);
}

__device__ inline bf16x8 ld_frag(const unsigned short* p) {
    uint4 u = *(const uint4*)p;
    return __builtin_bit_cast(bf16x8, u);
}

// ---------------------------------------------------------------------------
// Elementwise fp32 -> bf16 (x). One float4 per thread.
// ---------------------------------------------------------------------------
__global__ __launch_bounds__(256) void convert_f32_bf16(
    const float* __restrict__ in, unsigned short* __restrict__ out)
{
    const size_t idx = (size_t)blockIdx.x * 256 + threadIdx.x;
    float4 v = *(const float4*)(in + idx * 4);
    unsigned short* o = out + idx * 4;
    ushort4 r;
    r.x = f2bf(v.x); r.y = f2bf(v.y); r.z = f2bf(v.z); r.w = f2bf(v.w);
    *(ushort4*)o = r;
}

// ---------------------------------------------------------------------------
// Transpose + convert: in fp32 [K][N] -> out bf16 [N][K]. 64x64 tiles.
// ---------------------------------------------------------------------------
__global__ __launch_bounds__(256) void transpose_f32_bf16(
    const float* __restrict__ in, unsigned short* __restrict__ out,
    int K, int N)
{
    __shared__ float T[64][65];
    const int tid = threadIdx.x;
    const int k0 = blockIdx.y * 64, n0 = blockIdx.x * 64;
#pragma unroll
    for (int i = 0; i < 4; ++i) {
        int c = tid + i * 256;
        int row = c >> 4, col = (c & 15) << 2;
        float4 v = *(const float4*)(in + (size_t)(k0 + row) * N + n0 + col);
        T[row][col + 0] = v.x; T[row][col + 1] = v.y;
        T[row][col + 2] = v.z; T[row][col + 3] = v.w;
    }
    __syncthreads();
#pragma unroll
    for (int i = 0; i < 4; ++i) {
        int c = tid + i * 256;
        int nr = c >> 4, kc = (c & 15) << 2;
        ushort4 r;
        r.x = f2bf(T[kc + 0][nr]); r.y = f2bf(T[kc + 1][nr]);
        r.z = f2bf(T[kc + 2][nr]); r.w = f2bf(T[kc + 3][nr]);
        *(ushort4*)(out + (size_t)(n0 + nr) * K + k0 + kc) = r;
    }
}

// ---------------------------------------------------------------------------
// bf16 transpose of V into per-(b,h) key-major layout:
// v [4096][1024] (col = h*64+dim)  ->  vt [bh][dim][key].
// Grid (S/64, B*H), 256 threads.
// ---------------------------------------------------------------------------
__global__ __launch_bounds__(256) void transpose_v_bf16(
    const unsigned short* __restrict__ v,
    unsigned short* __restrict__ vt)
{
    __shared__ unsigned short T[64][65];
    const int tid = threadIdx.x;
    const int kt = blockIdx.x, bh = blockIdx.y;
    const int b = bh >> 4, h = bh & 15;
#pragma unroll
    for (int i = 0; i < 2; ++i) {
        const int c = tid + i * 256;
        const int key = c >> 3, off = (c & 7) << 3;
        uint4 u = *(const uint4*)(v + (size_t)(b * 1024 + kt * 64 + key) * 1024 + h * 64 + off);
        union { uint4 u4; unsigned short us[8]; } uu; uu.u4 = u;
#pragma unroll
        for (int t = 0; t < 8; ++t) T[key][off + t] = uu.us[t];
    }
    __syncthreads();
#pragma unroll
    for (int i = 0; i < 16; ++i) {
        const int c = tid + i * 256;          // 0..4095
        const int dim = c >> 6, key = c & 63;
        vt[((size_t)bh * 64 + dim) * 1024 + kt * 64 + key] = T[key][dim];
    }
}

// ---------------------------------------------------------------------------
// bf16 MFMA GEMM: C[M,N] = A[M,K] @ Bt[N,K]^T + bias.
// 128x128 tile, 4 waves (2x2). Staging: REG-STAGED uint4 copies into padded
// LDS [128][72] (conflict-free ds_read; R0 proven-fastest structure).
// MODE 0 (QKV): q (pre-scaled 1/8), k -> qk[row][head*128 + 0..127];
//               v -> vnat[row][head*64+dim] (coalesced; transposed later).
// MODE 1: fp32 out[M][N].
// ---------------------------------------------------------------------------
template<int MODE>
__global__ __launch_bounds__(256) void gemm_bf16(
    const unsigned short* __restrict__ A,
    const unsigned short* __restrict__ Bt,
    const float* __restrict__ bias,
    unsigned short* __restrict__ qk,
    unsigned short* __restrict__ vnat,
    float* __restrict__ out,
    int K, int N)
{
    __shared__ unsigned short Alds[128][72];
    __shared__ unsigned short Blds[128][72];
    const int tid  = threadIdx.x;
    const int l    = tid & 63, w = tid >> 6;
    const int wm   = w >> 1, wn = w & 1;
    const int quad = l >> 4, n16 = l & 15;
    const int bm = blockIdx.y * 128, bn = blockIdx.x * 128;

    const f32x4 zero4 = {0.f, 0.f, 0.f, 0.f};
    f32x4 acc[4][4];
#pragma unroll
    for (int i = 0; i < 4; ++i)
#pragma unroll
        for (int j = 0; j < 4; ++j) acc[i][j] = zero4;

    for (int k0 = 0; k0 < K; k0 += 64) {
#pragma unroll
        for (int i = 0; i < 4; ++i) {
            int c = tid + i * 256;
            int row = c >> 3, off = (c & 7) << 3;
            *(uint4*)&Alds[row][off] = *(const uint4*)(A + (size_t)(bm + row) * K + k0 + off);
            *(uint4*)&Blds[row][off] = *(const uint4*)(Bt + (size_t)(bn + row) * K + k0 + off);
        }
        __syncthreads();
#pragma unroll
        for (int kk = 0; kk < 2; ++kk) {
            const int kc = kk * 32 + quad * 8;
            bf16x8 af[4], bfv[4];
#pragma unroll
            for (int i = 0; i < 4; ++i) af[i]  = ld_frag(&Alds[wm * 64 + i * 16 + n16][kc]);
#pragma unroll
            for (int j = 0; j < 4; ++j) bfv[j] = ld_frag(&Blds[wn * 64 + j * 16 + n16][kc]);
#pragma unroll
            for (int i = 0; i < 4; ++i)
#pragma unroll
                for (int j = 0; j < 4; ++j)
                    acc[i][j] = MFMA16(af[i], bfv[j], acc[i][j]);
        }
        __syncthreads();
    }

    // epilogue
#pragma unroll
    for (int j = 0; j < 4; ++j) {
        const int col0 = bn + wn * 64 + j * 16;
        const int col  = col0 + n16;
        const float bv = bias ? bias[col] : 0.f;
        if (MODE == 0) {
            const int head = col0 / 192;
            const int rem  = col0 % 192;
            if (rem < 128) {
                // q columns (rem<64) carry the 1/sqrt(hd) logit scale so
                // attn_fused skips the per-logit multiply (exact in bf16).
                const float sc = (rem < 64) ? 0.125f : 1.0f;
#pragma unroll
                for (int i = 0; i < 4; ++i)
#pragma unroll
                    for (int r = 0; r < 4; ++r) {
                        int row = bm + wm * 64 + i * 16 + quad * 4 + r;
                        qk[(size_t)row * 2048 + head * 128 + rem + n16] =
                            f2bf((acc[i][j][r] + bv) * sc);
                    }
            } else {
                const int dcol = head * 64 + (rem - 128) + n16;
#pragma unroll
                for (int i = 0; i < 4; ++i)
#pragma unroll
                    for (int r = 0; r < 4; ++r) {
                        int row = bm + wm * 64 + i * 16 + quad * 4 + r;
                        vnat[(size_t)row * 1024 + dcol] = f2bf(acc[i][j][r] + bv);
                    }
            }
        } else {
#pragma unroll
            for (int i = 0; i < 4; ++i)
#pragma unroll
                for (int r = 0; r < 4; ++r) {
                    int row = bm + wm * 64 + i * 16 + quad * 4 + r;
                    out[(size_t)row * N + col] = acc[i][j][r] + bv;
                }
        }
    }
}

// ---------------------------------------------------------------------------
// Fused attention: per block = 16 Q-rows of one (b,h). 4 waves.
// Wave w consumes ONLY K-rows/V-dims w*16..w*16+15 of each 64-chunk, so
// K/V staging is WAVE-PRIVATE: each wave stages its own 2KB slice into its
// own LDS region — no __syncthreads in phases 1/3 (in-wave lgkmcnt ordering).
// Hand-pipelined T14-style: load(s+1)->regs, ds_read+MFMA(s), ds_write(s+1).
// Barriers: 2 (softmax reductions) + 1 (P handoff). Grid (S/16, B*H).
// ---------------------------------------------------------------------------
__global__ __launch_bounds__(256) void attn_fused(
    const unsigned short* __restrict__ qk,   // [4096][2048]
    const unsigned short* __restrict__ vt,   // [64][64][1024]
    float* __restrict__ attn,                // [64][1024][1024]
    unsigned short* __restrict__ values)     // [4096][1024]
{
    __shared__ unsigned short KVw[4][2][16][72];   // [wave][buf][row][col]
    __shared__ unsigned short Plds[16][1032];
    __shared__ float redbuf[2][4][16];

    const int qb = blockIdx.x, bh = blockIdx.y;
    const int b = bh >> 4, h = bh & 15;
    const int tid = threadIdx.x, l = tid & 63, w = tid >> 6;
    const int quad = l >> 4, n16 = l & 15;

    const int prow = l >> 3;            // 0..7
    const int poff = (l & 7) << 3;      // 0..56 (ushort col)

    // preload Q A-frags (q already scaled by 1/8 in gemm<0> epilogue)
    bf16x8 qf[2];
    {
        const unsigned short* qbase =
            qk + (size_t)(b * 1024 + qb * 16 + n16) * 2048 + h * 128 + quad * 8;
        qf[0] = ld_frag(qbase);
        qf[1] = ld_frag(qbase + 32);
    }

    const f32x4 zero4 = {0.f, 0.f, 0.f, 0.f};
    f32x4 c[16];
#pragma unroll
    for (int s = 0; s < 16; ++s) c[s] = zero4;

    // ---- Phase 1: QK^T, wave-private dbuf staging, barrier-free ----
    // wave w stages K rows s*64 + w*16 + (0..15): 16 rows x 128B = 2 uint4/lane
    const unsigned short* kwbase =
        qk + (size_t)(b * 1024 + w * 16) * 2048 + h * 128 + 64;
    {
        uint4 r0 = *(const uint4*)(kwbase + (size_t)prow * 2048 + poff);
        uint4 r1 = *(const uint4*)(kwbase + (size_t)(prow + 8) * 2048 + poff);
        *(uint4*)&KVw[w][0][prow][poff]     = r0;
        *(uint4*)&KVw[w][0][prow + 8][poff] = r1;
    }
    for (int s = 0; s < 16; ++s) {
        uint4 n0, n1;
        if (s < 15) {
            const unsigned short* p = kwbase + (size_t)(s + 1) * 64 * 2048;
            n0 = *(const uint4*)(p + (size_t)prow * 2048 + poff);
            n1 = *(const uint4*)(p + (size_t)(prow + 8) * 2048 + poff);
        }
        const int pb = s & 1;
        bf16x8 k0f = ld_frag(&KVw[w][pb][n16][quad * 8]);
        bf16x8 k1f = ld_frag(&KVw[w][pb][n16][32 + quad * 8]);
        c[s] = MFMA16(qf[0], k0f, c[s]);
        c[s] = MFMA16(qf[1], k1f, c[s]);
        if (s < 15) {
            *(uint4*)&KVw[w][pb ^ 1][prow][poff]     = n0;
            *(uint4*)&KVw[w][pb ^ 1][prow + 8][poff] = n1;
        }
    }

    // ---- Phase 2: softmax in registers ----
    float mx[4] = {-1e30f, -1e30f, -1e30f, -1e30f};
#pragma unroll
    for (int s = 0; s < 16; ++s)
#pragma unroll
        for (int r = 0; r < 4; ++r)
            mx[r] = fmaxf(mx[r], c[s][r]);
#pragma unroll
    for (int off = 1; off <= 8; off <<= 1)
#pragma unroll
        for (int r = 0; r < 4; ++r)
            mx[r] = fmaxf(mx[r], __shfl_xor(mx[r], off, 64));
    if (n16 == 0)
#pragma unroll
        for (int r = 0; r < 4; ++r) redbuf[0][w][quad * 4 + r] = mx[r];
    __syncthreads();
#pragma unroll
    for (int r = 0; r < 4; ++r) {
        const int row = quad * 4 + r;
        float m = redbuf[0][0][row];
        m = fmaxf(m, redbuf[0][1][row]);
        m = fmaxf(m, redbuf[0][2][row]);
        m = fmaxf(m, redbuf[0][3][row]);
        mx[r] = m;
    }

    float sm[4] = {0.f, 0.f, 0.f, 0.f};
#pragma unroll
    for (int s = 0; s < 16; ++s)
#pragma unroll
        for (int r = 0; r < 4; ++r) {
            float e = __expf(c[s][r] - mx[r]);
            c[s][r] = e;
            sm[r] += e;
        }
#pragma unroll
    for (int off = 1; off <= 8; off <<= 1)
#pragma unroll
        for (int r = 0; r < 4; ++r)
            sm[r] += __shfl_xor(sm[r], off, 64);
    if (n16 == 0)
#pragma unroll
        for (int r = 0; r < 4; ++r) redbuf[1][w][quad * 4 + r] = sm[r];
    __syncthreads();
    float inv[4];
#pragma unroll
    for (int r = 0; r < 4; ++r) {
        const int row = quad * 4 + r;
        inv[r] = 1.f / (redbuf[1][0][row] + redbuf[1][1][row] +
                        redbuf[1][2][row] + redbuf[1][3][row]);
    }

    // write attention (fp32) + P (bf16 to LDS for AV)
    float* abase = attn + ((size_t)bh * 1024 + qb * 16) * 1024;
#pragma unroll
    for (int s = 0; s < 16; ++s)
#pragma unroll
        for (int r = 0; r < 4; ++r) {
            const float a = c[s][r] * inv[r];
            const int row = quad * 4 + r;
            const int key = s * 64 + w * 16 + n16;
            abase[(size_t)row * 1024 + key] = a;
            Plds[row][key] = f2bf(a);
        }
    __syncthreads();    // P handoff (cross-wave columns)

    // ---- Phase 3: AV, wave-private dbuf staging, barrier-free ----
    // wave w stages V dims w*16 + (0..15), keys s*64..+64
    f32x4 o = zero4;
    const unsigned short* vwbase = vt + (size_t)bh * 65536 +
                                   (size_t)(w * 16) * 1024;
    {
        uint4 r0 = *(const uint4*)(vwbase + (size_t)prow * 1024 + poff);
        uint4 r1 = *(const uint4*)(vwbase + (size_t)(prow + 8) * 1024 + poff);
        *(uint4*)&KVw[w][0][prow][poff]     = r0;
        *(uint4*)&KVw[w][0][prow + 8][poff] = r1;
    }
    for (int s = 0; s < 16; ++s) {
        uint4 n0, n1;
        if (s < 15) {
            const unsigned short* p = vwbase + (s + 1) * 64;
            n0 = *(const uint4*)(p + (size_t)prow * 1024 + poff);
            n1 = *(const uint4*)(p + (size_t)(prow + 8) * 1024 + poff);
        }
        const int pb = s & 1;
#pragma unroll
        for (int kk = 0; kk < 2; ++kk) {
            bf16x8 pf = ld_frag(&Plds[n16][s * 64 + kk * 32 + quad * 8]);
            bf16x8 vf = ld_frag(&KVw[w][pb][n16][kk * 32 + quad * 8]);
            o = MFMA16(pf, vf, o);
        }
        if (s < 15) {
            *(uint4*)&KVw[w][pb ^ 1][prow][poff]     = n0;
            *(uint4*)&KVw[w][pb ^ 1][prow + 8][poff] = n1;
        }
    }

#pragma unroll
    for (int r = 0; r < 4; ++r) {
        const int row = quad * 4 + r;
        values[(size_t)(b * 1024 + qb * 16 + row) * 1024 + h * 64 + w * 16 + n16] =
            f2bf(o[r]);
    }
}

// ---------------------------------------------------------------------------
extern "C" void kernel_launch(void* const* d_in, const int* in_sizes, int n_in,
                              void* d_out, int out_size, void* d_ws, size_t ws_size,
                              hipStream_t stream)
{
    const float* x     = (const float*)d_in[0];   // [4,1024,1024]
    const float* W_qkv = (const float*)d_in[1];   // [1024,3072]
    const float* b_qkv = (const float*)d_in[2];   // [3072]
    const float* W_o   = (const float*)d_in[3];   // [1024,1024]
    const float* b_o   = (const float*)d_in[4];   // [1024]

    float* o_out    = (float*)d_out;                          // [4096,1024] fp32
    float* attn_out = o_out + (size_t)B_ * S_ * D_;           // [64,1024,1024] fp32

    const size_t M1 = 1ull << 20;
    unsigned short* ws      = (unsigned short*)d_ws;
    unsigned short* x_bf    = ws;                 // 4M  [4096][1024]
    unsigned short* wqkvt   = ws + 4 * M1;        // 3M  [3072][1024]
    unsigned short* wot     = ws + 7 * M1;        // 1M  [1024][1024]
    unsigned short* qkbuf   = ws + 8 * M1;        // 8M  [4096][2048]
    unsigned short* vtbuf   = ws + 16 * M1;       // 4M  [64][64][1024]
    unsigned short* valbuf  = ws + 20 * M1;       // 4M  [4096][1024] (vnat, then values)

    convert_f32_bf16<<<4096, 256, 0, stream>>>(x, x_bf);
    transpose_f32_bf16<<<dim3(3072 / 64, 1024 / 64), 256, 0, stream>>>(W_qkv, wqkvt, 1024, 3072);
    transpose_f32_bf16<<<dim3(1024 / 64, 1024 / 64), 256, 0, stream>>>(W_o, wot, 1024, 1024);

    gemm_bf16<0><<<dim3(3072 / 128, 4096 / 128), 256, 0, stream>>>(
        x_bf, wqkvt, b_qkv, qkbuf, valbuf, nullptr, 1024, 3072);

    transpose_v_bf16<<<dim3(S_ / 64, B_ * H_), 256, 0, stream>>>(valbuf, vtbuf);

    attn_fused<<<dim3(S_ / 16, B_ * H_), 256, 0, stream>>>(
        qkbuf, vtbuf, attn_out, valbuf);

    gemm_bf16<1><<<dim3(1024 / 128, 4096 / 128), 256, 0, stream>>>(
        valbuf, wot, b_o, nullptr, nullptr, o_out, 1024, 1024);
}